// Round 5
// baseline (2866.232 us; speedup 1.0000x reference)
//
#include <hip/hip_runtime.h>
#include <math.h>

typedef unsigned int u32;
typedef unsigned short u16;

#define NS 128          // T-1 timesteps
#define A_ 5
#define B_ 128
#define NTH 1024
#define NWG 160         // 5 agents x 32 chunks of 4 rows
#define LOG2PI_F 1.8378770664093453f

// ---- packed weight layout (uint2 = 4 f16 units), per agent ----
// U-layers use the unified 160-elem input [x2 y10 z16 pad4 h128] = 40 quads,
// with zero weights where a layer doesn't consume a slot.
#define OF_E1 0         // 40q x 128
#define OF_P1 5120
#define OF_D1 10240
#define OF_G  15360     // 40q x 384 (3 gates x 128)
#define OF_E2 30720     // 32q x 128
#define OF_P2 34816
#define OF_D2 38912
#define OF_H  43008     // 4 heads x (32q x 16)
#define OF_DH 45056     // 2 heads x (32q x 2)
#define AGU2  45184

typedef _Float16 half2v __attribute__((ext_vector_type(2)));

__device__ __forceinline__ float fdot2(u32 w, u32 x, float acc) {
#if __has_builtin(__builtin_amdgcn_fdot2)
    return __builtin_amdgcn_fdot2(__builtin_bit_cast(half2v, w),
                                  __builtin_bit_cast(half2v, x), acc, false);
#else
    half2v a = __builtin_bit_cast(half2v, w), b = __builtin_bit_cast(half2v, x);
    return acc + (float)a.x * (float)b.x + (float)a.y * (float)b.y;
#endif
}
__device__ __forceinline__ u16 f2h(float f) { _Float16 h = (_Float16)f; return __builtin_bit_cast(u16, h); }
__device__ __forceinline__ float h2f(u16 u) { return (float)__builtin_bit_cast(_Float16, u); }
__device__ __forceinline__ float softplusf_(float x) { return fmaxf(x, 0.f) + log1pf(expf(-fabsf(x))); }
__device__ __forceinline__ float sigmoidf_(float x) { return 1.f / (1.f + expf(-x)); }

// reduce over kq (lane bits 3,4,5)
#define RED8(v)  { v += __shfl_xor(v, 8); v += __shfl_xor(v, 16); v += __shfl_xor(v, 32); }
// reduce over ks (lane bits 4,5)
#define REDH(v)  { v += __shfl_xor(v, 16); v += __shfl_xor(v, 32); }
#define SEL4(k, v0, v1, v2, v3) ((k)==0 ? (v0) : (k)==1 ? (v1) : (k)==2 ? (v2) : (v3))
#define PINU2(w) asm volatile("" : "+v"((w).x), "+v"((w).y))
#define PINF(f)  asm volatile("" : "+v"(f))

struct P5s {
    const float* __restrict__ y;
    const float* __restrict__ eps;
    const float* __restrict__ eb1; const float* __restrict__ eb2;
    const float* __restrict__ pb1; const float* __restrict__ pb2;
    const float* __restrict__ db1; const float* __restrict__ db2;
    const float* __restrict__ emb; const float* __restrict__ esb;
    const float* __restrict__ pmb; const float* __restrict__ psb;
    const float* __restrict__ dmb; const float* __restrict__ dsb;
    const float* __restrict__ bih; const float* __restrict__ bhh;
    const uint2* __restrict__ wq;
    float* __restrict__ partials;
};

__global__ void __launch_bounds__(NTH, 4) vrnn5(P5s p) {
    const int tid = threadIdx.x;
    const int a = blockIdx.x >> 5;
    const int b0 = (blockIdx.x & 31) * 4;
    const int wave = tid >> 6;               // 0..15
    const int lane = tid & 63;
    const int ol = lane & 7;
    const int kq = lane >> 3;                // K-eighth 0..7
    const int o = wave * 8 + ol;             // output column 0..127
    const bool k0 = (kq == 0);
    const int kr = kq & 3;                   // row alias for writers (kq<4)

    __shared__ __align__(16) u16 U[4][160];          // [x2 y10 z16 pad4 h128]
    __shared__ __align__(16) u16 aA[4][128], aB[4][128], aC[4][128], aD[4][128];
    __shared__ float mue[4][16], sde[4][16], mup[4][16], sdp[4][16];
    __shared__ float xf[4][2], dmu[4][2], dsd[4][2];
    __shared__ uint2 whP[4 * 544];   // 4 heads x 32q x (16+pad1) -> conflict-free
    __shared__ uint2 wdhLDS[128];    // 2 heads x 32q x 2
    __shared__ float red[NTH];

    const uint2* WA = p.wq + (size_t)a * AGU2;

    // ---- init LDS ----
    if (tid < 4 * 160) (&U[0][0])[tid] = 0;
    for (int i = tid; i < 2048; i += NTH) {
        int hh = i >> 9, rem = i & 511, q = rem >> 4, zd = rem & 15;
        whP[hh * 544 + q * 17 + zd] = WA[OF_H + i];
    }
    if (tid < 128) wdhLDS[tid] = WA[OF_DH + tid];

    // ---- register-resident weights: interleaved K-slices q = kq + 8j ----
    uint2 wE1[5], wP1[5], wD1[5], wG0[5], wG1[5], wG2[5];
    uint2 wE2[4], wP2[4], wD2[4];
#pragma unroll
    for (int j = 0; j < 5; ++j) {
        int q = kq + 8 * j;
        wE1[j] = WA[OF_E1 + q * 128 + o];
        wP1[j] = WA[OF_P1 + q * 128 + o];
        wD1[j] = WA[OF_D1 + q * 128 + o];
        wG0[j] = WA[OF_G + q * 384 + o];
        wG1[j] = WA[OF_G + q * 384 + 128 + o];
        wG2[j] = WA[OF_G + q * 384 + 256 + o];
    }
#pragma unroll
    for (int j = 0; j < 4; ++j) {
        int q = kq + 8 * j;
        wE2[j] = WA[OF_E2 + q * 128 + o];
        wP2[j] = WA[OF_P2 + q * 128 + o];
        wD2[j] = WA[OF_D2 + q * 128 + o];
    }
#pragma unroll
    for (int j = 0; j < 5; ++j) {
        PINU2(wE1[j]); PINU2(wP1[j]); PINU2(wD1[j]);
        PINU2(wG0[j]); PINU2(wG1[j]); PINU2(wG2[j]);
    }
#pragma unroll
    for (int j = 0; j < 4; ++j) { PINU2(wE2[j]); PINU2(wP2[j]); PINU2(wD2[j]); }

    // ---- register-resident biases ----
    float rbE1 = p.eb1[a * 128 + o], rbE2 = p.eb2[a * 128 + o];
    float rbP1 = p.pb1[a * 128 + o], rbP2 = p.pb2[a * 128 + o];
    float rbD1 = p.db1[a * 128 + o], rbD2 = p.db2[a * 128 + o];
    float rbI0 = p.bih[a * 384 + o], rbI1 = p.bih[a * 384 + 128 + o], rbI2 = p.bih[a * 384 + 256 + o];
    float rbH0 = p.bhh[a * 384 + o], rbH1 = p.bhh[a * 384 + 128 + o], rbH2 = p.bhh[a * 384 + 256 + o];
    const int headH = wave & 3, rowH = wave >> 2, zdH = lane & 15, ksH = lane >> 4;
    float rbH = ((headH == 0) ? p.emb : (headH == 1) ? p.esb
               : (headH == 2) ? p.pmb : p.psb)[a * 16 + zdH];
    const int headD = wave >> 3, subD = wave & 7, rD = subD >> 1, xdD = subD & 1;
    float rbDH = (headD ? p.dsb : p.dmb)[a * 2 + xdD];
    PINF(rbE1); PINF(rbE2); PINF(rbP1); PINF(rbP2); PINF(rbD1); PINF(rbD2);
    PINF(rbI0); PINF(rbI1); PINF(rbI2); PINF(rbH0); PINF(rbH1); PINF(rbH2);
    PINF(rbH); PINF(rbDH);

    // ---- prefetch t=0 inputs into registers ----
    const int ry = tid / 10, jy = tid - ry * 10;            // tid<40
    const int rx = (tid - 40) >> 1, xdx = (tid - 40) & 1;   // 40<=tid<48
    const int re = tid >> 4, ze = tid & 15;                 // tid<64
    float ypre = 0.f, xpre = 0.f, epre = 0.f;
    if (tid < 40) ypre = p.y[0 * (B_ * 10) + (b0 + ry) * 10 + jy];
    else if (tid < 48) xpre = p.y[1 * (B_ * 10) + (b0 + rx) * 10 + a * 2 + xdx];
    if (tid < 64) epre = p.eps[(((size_t)0 * A_ + a) * B_ + (b0 + re)) * 16 + ze];

    float kl_acc = 0.f, nll_acc = 0.f, hnew = 0.f;

#pragma unroll 1
    for (int t = 0; t < NS; ++t) {
        const int tn = (t + 1 < NS) ? t + 1 : t;
        __syncthreads();
        // ---- P1: commit prefetched inputs, issue next prefetch ----
        if (tid < 40) {
            U[ry][2 + jy] = f2h(ypre);
            ypre = p.y[tn * (B_ * 10) + (b0 + ry) * 10 + jy];
        } else if (tid < 48) {
            U[rx][xdx] = f2h(xpre); xf[rx][xdx] = xpre;
            xpre = p.y[(tn + 1) * (B_ * 10) + (b0 + rx) * 10 + a * 2 + xdx];
        }
        __syncthreads();

        // ---- P2: enc1 + pri1 (shared U reads, 5 interleaved quads each) ----
        {
            float aE[4], aP[4];
#pragma unroll
            for (int r = 0; r < 4; ++r) { aE[r] = k0 ? rbE1 : 0.f; aP[r] = k0 ? rbP1 : 0.f; }
#pragma unroll
            for (int j = 0; j < 5; ++j) {
#pragma unroll
                for (int r = 0; r < 4; ++r) {
                    uint2 xv = *(const uint2*)(&U[r][0] + kq * 4 + j * 32);
                    aE[r] = fdot2(wE1[j].x, xv.x, aE[r]);
                    aE[r] = fdot2(wE1[j].y, xv.y, aE[r]);
                    aP[r] = fdot2(wP1[j].x, xv.x, aP[r]);
                    aP[r] = fdot2(wP1[j].y, xv.y, aP[r]);
                }
            }
#pragma unroll
            for (int r = 0; r < 4; ++r) { RED8(aE[r]); RED8(aP[r]); }
            if (kq < 4) {
                float vE = SEL4(kr, aE[0], aE[1], aE[2], aE[3]);
                float vP = SEL4(kr, aP[0], aP[1], aP[2], aP[3]);
                aA[kr][o] = f2h(fmaxf(vE, 0.f));
                aC[kr][o] = f2h(fmaxf(vP, 0.f));
            }
        }
        __syncthreads();

        // ---- P3: enc2 (aA->aB), pri2 (aC->aD) ----
        {
            float aE[4], aP[4];
#pragma unroll
            for (int r = 0; r < 4; ++r) { aE[r] = k0 ? rbE2 : 0.f; aP[r] = k0 ? rbP2 : 0.f; }
#pragma unroll
            for (int j = 0; j < 4; ++j) {
#pragma unroll
                for (int r = 0; r < 4; ++r) {
                    uint2 xa = *(const uint2*)(&aA[r][0] + kq * 4 + j * 32);
                    uint2 xc = *(const uint2*)(&aC[r][0] + kq * 4 + j * 32);
                    aE[r] = fdot2(wE2[j].x, xa.x, aE[r]);
                    aE[r] = fdot2(wE2[j].y, xa.y, aE[r]);
                    aP[r] = fdot2(wP2[j].x, xc.x, aP[r]);
                    aP[r] = fdot2(wP2[j].y, xc.y, aP[r]);
                }
            }
#pragma unroll
            for (int r = 0; r < 4; ++r) { RED8(aE[r]); RED8(aP[r]); }
            if (kq < 4) {
                float vE = SEL4(kr, aE[0], aE[1], aE[2], aE[3]);
                float vP = SEL4(kr, aP[0], aP[1], aP[2], aP[3]);
                aB[kr][o] = f2h(fmaxf(vE, 0.f));
                aD[kr][o] = f2h(fmaxf(vP, 0.f));
            }
        }
        __syncthreads();

        // ---- P4: 4 gaussian heads (128->16), 1 (head,row) per wave ----
        {
            const u16* src = (headH < 2) ? &aB[rowH][0] : &aD[rowH][0];
            float e0 = (ksH == 0) ? rbH : 0.f;
#pragma unroll
            for (int j = 0; j < 8; ++j) {
                int q = ksH + 4 * j;
                uint2 w = whP[headH * 544 + q * 17 + zdH];
                uint2 xv = *(const uint2*)(src + q * 4);
                e0 = fdot2(w.x, xv.x, e0);
                e0 = fdot2(w.y, xv.y, e0);
            }
            REDH(e0);
            if (ksH == 0) {
                if (headH == 0)      mue[rowH][zdH] = e0;
                else if (headH == 1) sde[rowH][zdH] = softplusf_(e0);
                else if (headH == 2) mup[rowH][zdH] = e0;
                else                 sdp[rowH][zdH] = softplusf_(e0);
            }
        }
        __syncthreads();

        // ---- P5: z sample + KL (eps was prefetched) ----
        if (tid < 64) {
            float em = mue[re][ze], es = sde[re][ze], pm = mup[re][ze], ps = sdp[re][ze];
            float zv = fmaf(epre, es, em);
            U[re][12 + ze] = f2h(zv);
            float dm = em - pm;
            kl_acc += 0.5f * (2.f * (logf(ps) - logf(es)) + (es * es + dm * dm) / (ps * ps) - 1.f);
            epre = p.eps[(((size_t)tn * A_ + a) * B_ + (b0 + re)) * 16 + ze];
        }
        __syncthreads();

        // ---- P6: dec1 + GRU (shared U reads; j==0 is the ih region) ----
        {
            float aO[4], s0[4], s1[4], g2i[4], g2h[4];
#pragma unroll
            for (int r = 0; r < 4; ++r) {
                aO[r]  = k0 ? rbD1 : 0.f;
                s0[r]  = k0 ? (rbI0 + rbH0) : 0.f;
                s1[r]  = k0 ? (rbI1 + rbH1) : 0.f;
                g2i[r] = k0 ? rbI2 : 0.f;
                g2h[r] = k0 ? rbH2 : 0.f;
            }
#pragma unroll
            for (int j = 0; j < 5; ++j) {
#pragma unroll
                for (int r = 0; r < 4; ++r) {
                    uint2 xv = *(const uint2*)(&U[r][0] + kq * 4 + j * 32);
                    aO[r] = fdot2(wD1[j].x, xv.x, aO[r]);
                    aO[r] = fdot2(wD1[j].y, xv.y, aO[r]);
                    s0[r] = fdot2(wG0[j].x, xv.x, s0[r]);
                    s0[r] = fdot2(wG0[j].y, xv.y, s0[r]);
                    s1[r] = fdot2(wG1[j].x, xv.x, s1[r]);
                    s1[r] = fdot2(wG1[j].y, xv.y, s1[r]);
                    if (j == 0) {
                        g2i[r] = fdot2(wG2[j].x, xv.x, g2i[r]);
                        g2i[r] = fdot2(wG2[j].y, xv.y, g2i[r]);
                    } else {
                        g2h[r] = fdot2(wG2[j].x, xv.x, g2h[r]);
                        g2h[r] = fdot2(wG2[j].y, xv.y, g2h[r]);
                    }
                }
            }
#pragma unroll
            for (int r = 0; r < 4; ++r) {
                RED8(aO[r]); RED8(s0[r]); RED8(s1[r]); RED8(g2i[r]); RED8(g2h[r]);
            }
            float vD  = SEL4(kr, aO[0], aO[1], aO[2], aO[3]);
            float rs  = SEL4(kr, s0[0], s0[1], s0[2], s0[3]);
            float zs  = SEL4(kr, s1[0], s1[1], s1[2], s1[3]);
            float i2  = SEL4(kr, g2i[0], g2i[1], g2i[2], g2i[3]);
            float hh2 = SEL4(kr, g2h[0], g2h[1], g2h[2], g2h[3]);
            float rr = sigmoidf_(rs);
            float zz = sigmoidf_(zs);
            float nn = tanhf(fmaf(rr, hh2, i2));
            float hold = h2f(U[kr][32 + o]);
            hnew = fmaf(zz, hold - nn, nn);
            if (kq < 4) aA[kr][o] = f2h(fmaxf(vD, 0.f));
        }
        __syncthreads();

        // ---- P7: dec2 (aA -> aB) ----
        {
            float aE[4];
#pragma unroll
            for (int r = 0; r < 4; ++r) aE[r] = k0 ? rbD2 : 0.f;
#pragma unroll
            for (int j = 0; j < 4; ++j) {
#pragma unroll
                for (int r = 0; r < 4; ++r) {
                    uint2 xa = *(const uint2*)(&aA[r][0] + kq * 4 + j * 32);
                    aE[r] = fdot2(wD2[j].x, xa.x, aE[r]);
                    aE[r] = fdot2(wD2[j].y, xa.y, aE[r]);
                }
            }
#pragma unroll
            for (int r = 0; r < 4; ++r) RED8(aE[r]);
            if (kq < 4) {
                float vE = SEL4(kr, aE[0], aE[1], aE[2], aE[3]);
                aB[kr][o] = f2h(fmaxf(vE, 0.f));
            }
        }
        __syncthreads();

        // ---- P8: h write + dec heads (128->2, one output per wave) ----
        if (kq < 4) U[kr][32 + o] = f2h(hnew);
        {
            u32 w = ((const u32*)wdhLDS)[headD * 128 + (lane >> 1) * 4 + xdD * 2 + (lane & 1)];
            u32 xv = ((const u32*)&aB[rD][0])[lane];
            float s = fdot2(w, xv, 0.f);
            s += __shfl_xor(s, 1); s += __shfl_xor(s, 2); s += __shfl_xor(s, 4);
            s += __shfl_xor(s, 8); s += __shfl_xor(s, 16); s += __shfl_xor(s, 32);
            if (lane == 0) {
                float v = rbDH + s;
                if (headD) dsd[rD][xdD] = softplusf_(v);
                else       dmu[rD][xdD] = v;
            }
        }
        __syncthreads();

        // ---- P9: NLL ----
        if (tid < 8) {
            int r = tid >> 1, xd = tid & 1;
            float d = xf[r][xd] - dmu[r][xd];
            float sd = dsd[r][xd];
            nll_acc += 0.5f * (d * d / (sd * sd) + 2.f * logf(sd) + LOG2PI_F);
        }
    }

    // ---- block reductions ----
    __syncthreads();
    red[tid] = kl_acc; __syncthreads();
    for (int s2 = NTH / 2; s2 > 0; s2 >>= 1) {
        if (tid < s2) red[tid] += red[tid + s2];
        __syncthreads();
    }
    if (tid == 0) p.partials[blockIdx.x] = red[0];
    __syncthreads();
    red[tid] = nll_acc; __syncthreads();
    for (int s2 = NTH / 2; s2 > 0; s2 >>= 1) {
        if (tid < s2) red[tid] += red[tid + s2];
        __syncthreads();
    }
    if (tid == 0) p.partials[NWG + blockIdx.x] = red[0];
}

// ---------------- prep: pack weights into unified zero-padded f16 quads ----------------
struct PrepP {
    const float* eW1; const float* pW1; const float* dW1;
    const float* wih; const float* whh;
    const float* eW2; const float* pW2; const float* dW2;
    const float* hW[4];   // em es pm ps
    const float* dHW[2];  // dm ds
    uint2* dst;
};

__global__ void prep3(PrepP pp) {
    const int jod[13]  = {128,128,128,384, 128,128,128, 16,16,16,16, 2,2};
    const int jnq[13]  = {40,40,40,40, 32,32,32, 32,32,32,32, 32,32};
    const int jdst[13] = {OF_E1,OF_P1,OF_D1,OF_G, OF_E2,OF_P2,OF_D2,
                          OF_H,OF_H+512,OF_H+1024,OF_H+1536, OF_DH,OF_DH+64};
    const int jkt[3]   = {140,138,154};

    int job = blockIdx.y;
    int od = jod[job], nq = jnq[job];
    int total = A_ * nq * od;
    int idx = blockIdx.x * 256 + threadIdx.x;
    if (idx >= total) return;
    int a = idx / (nq * od);
    int rem = idx - a * (nq * od);
    int q = rem / od;
    int c = rem - q * od;

    float v[4];
#pragma unroll
    for (int i = 0; i < 4; ++i) {
        int k = 4 * q + i;
        float val = 0.f;
        if (job < 3) {
            // unified u index -> source row
            int sk = -1;
            if (job == 0)      sk = (k < 12) ? k : (k >= 32 ? k - 20 : -1);
            else if (job == 1) sk = (k >= 2 && k < 12) ? k - 2 : (k >= 32 ? k - 22 : -1);
            else               sk = (k >= 2 && k < 28) ? k - 2 : (k >= 32 ? k - 6 : -1);
            const float* s = (job == 0) ? pp.eW1 : (job == 1) ? pp.pW1 : pp.dW1;
            if (sk >= 0) val = s[((size_t)a * jkt[job] + sk) * 128 + c];
        } else if (job == 3) {
            // GRU unified: c = gate index 0..383
            if (k < 2)                  val = pp.wih[((size_t)a * 384 + c) * 18 + k];
            else if (k >= 12 && k < 28) val = pp.wih[((size_t)a * 384 + c) * 18 + (k - 10)];
            else if (k >= 32)           val = pp.whh[((size_t)a * 384 + c) * 128 + (k - 32)];
        } else {
            const float* s = (job == 4) ? pp.eW2 : (job == 5) ? pp.pW2 : (job == 6) ? pp.dW2
                           : (job <= 10) ? pp.hW[job - 7] : pp.dHW[job - 11];
            val = s[((size_t)a * 128 + k) * od + c];
        }
        v[i] = val;
    }
    u32 lo = (u32)f2h(v[0]) | ((u32)f2h(v[1]) << 16);
    u32 hi = (u32)f2h(v[2]) | ((u32)f2h(v[3]) << 16);
    pp.dst[(size_t)a * AGU2 + jdst[job] + q * od + c] = make_uint2(lo, hi);
}

__global__ void finish_kernel(const float* __restrict__ partials, float* __restrict__ out) {
    __shared__ float red[256];
    int tid = threadIdx.x;
    red[tid] = (tid < NWG) ? partials[tid] : 0.f;
    __syncthreads();
    for (int s2 = 128; s2 > 0; s2 >>= 1) {
        if (tid < s2) red[tid] += red[tid + s2];
        __syncthreads();
    }
    if (tid == 0) out[0] = red[0];
    __syncthreads();
    red[tid] = (tid < NWG) ? partials[NWG + tid] : 0.f;
    __syncthreads();
    for (int s2 = 128; s2 > 0; s2 >>= 1) {
        if (tid < s2) red[tid] += red[tid + s2];
        __syncthreads();
    }
    if (tid == 0) out[1] = red[0];
}

extern "C" void kernel_launch(void* const* d_in, const int* in_sizes, int n_in,
                              void* d_out, int out_size, void* d_ws, size_t ws_size,
                              hipStream_t stream) {
    float* partials = (float*)d_ws;                 // 320 floats
    uint2* wq = (uint2*)((char*)d_ws + 4096);       // packed weights, ~1.81 MB

    PrepP pp;
    pp.eW1 = (const float*)d_in[2];
    pp.pW1 = (const float*)d_in[10];
    pp.dW1 = (const float*)d_in[18];
    pp.wih = (const float*)d_in[26];
    pp.whh = (const float*)d_in[27];
    pp.eW2 = (const float*)d_in[4];
    pp.pW2 = (const float*)d_in[12];
    pp.dW2 = (const float*)d_in[20];
    pp.hW[0] = (const float*)d_in[6];   // emW
    pp.hW[1] = (const float*)d_in[8];   // esW
    pp.hW[2] = (const float*)d_in[14];  // pmW
    pp.hW[3] = (const float*)d_in[16];  // psW
    pp.dHW[0] = (const float*)d_in[22]; // dmW
    pp.dHW[1] = (const float*)d_in[24]; // dsW
    pp.dst = wq;
    // max job total = 5*40*384 = 76800 -> 300 blocks x 256, y = 13 jobs
    prep3<<<dim3(300, 13), 256, 0, stream>>>(pp);

    P5s p;
    p.y   = (const float*)d_in[0];
    p.eps = (const float*)d_in[1];
    p.eb1 = (const float*)d_in[3];  p.eb2 = (const float*)d_in[5];
    p.emb = (const float*)d_in[7];  p.esb = (const float*)d_in[9];
    p.pb1 = (const float*)d_in[11]; p.pb2 = (const float*)d_in[13];
    p.pmb = (const float*)d_in[15]; p.psb = (const float*)d_in[17];
    p.db1 = (const float*)d_in[19]; p.db2 = (const float*)d_in[21];
    p.dmb = (const float*)d_in[23]; p.dsb = (const float*)d_in[25];
    p.bih = (const float*)d_in[28]; p.bhh = (const float*)d_in[29];
    p.wq = wq;
    p.partials = partials;

    vrnn5<<<NWG, NTH, 0, stream>>>(p);
    finish_kernel<<<1, 256, 0, stream>>>(partials, (float*)d_out);
}

// Round 6
// 1030.385 us; speedup vs baseline: 2.7817x; 2.7817x over previous
//
#include <hip/hip_runtime.h>
#include <math.h>

typedef unsigned int u32;
typedef unsigned short u16;

#define NS 128          // T-1 timesteps
#define A_ 5
#define B_ 128
#define NTH 512
#define NWG 160         // 5 agents x 32 chunks of 4 rows
#define LOG2PI_F 1.8378770664093453f

// ---- packed weight layout (uint2 = 4 f16 units), per agent ----
// U-layers use the unified 160-elem input [x2 y10 z16 pad4 h128] = 40 quads,
// with zero weights where a layer doesn't consume a slot.
#define OF_E1 0         // 40q x 128
#define OF_P1 5120
#define OF_D1 10240
#define OF_G  15360     // 40q x 384 (3 gates x 128)
#define OF_E2 30720     // 32q x 128
#define OF_P2 34816
#define OF_D2 38912
#define OF_H  43008     // 4 heads x (32q x 16)
#define OF_DH 45056     // 2 heads x (32q x 2)
#define AGU2  45184

typedef _Float16 half2v __attribute__((ext_vector_type(2)));

__device__ __forceinline__ float fdot2(u32 w, u32 x, float acc) {
#if __has_builtin(__builtin_amdgcn_fdot2)
    return __builtin_amdgcn_fdot2(__builtin_bit_cast(half2v, w),
                                  __builtin_bit_cast(half2v, x), acc, false);
#else
    half2v a = __builtin_bit_cast(half2v, w), b = __builtin_bit_cast(half2v, x);
    return acc + (float)a.x * (float)b.x + (float)a.y * (float)b.y;
#endif
}
__device__ __forceinline__ u16 f2h(float f) { _Float16 h = (_Float16)f; return __builtin_bit_cast(u16, h); }
__device__ __forceinline__ float h2f(u16 u) { return (float)__builtin_bit_cast(_Float16, u); }
__device__ __forceinline__ float softplusf_(float x) { return fmaxf(x, 0.f) + log1pf(expf(-fabsf(x))); }
__device__ __forceinline__ float sigmoidf_(float x) { return 1.f / (1.f + expf(-x)); }

#define RED16_32(v) { v += __shfl_xor(v, 16); v += __shfl_xor(v, 32); }
#define SEL4(k, v0, v1, v2, v3) ((k)==0 ? (v0) : (k)==1 ? (v1) : (k)==2 ? (v2) : (v3))
// Pin a value into a VGPR: opaque to the optimizer, so loop-invariant loads
// cannot be sunk back into the t-loop.
#define PINU2(w) asm volatile("" : "+v"((w).x), "+v"((w).y))
#define PINF(f)  asm volatile("" : "+v"(f))

struct P3s {
    const float* __restrict__ y;
    const float* __restrict__ eps;
    const float* __restrict__ eb1; const float* __restrict__ eb2;
    const float* __restrict__ pb1; const float* __restrict__ pb2;
    const float* __restrict__ db1; const float* __restrict__ db2;
    const float* __restrict__ emb; const float* __restrict__ esb;
    const float* __restrict__ pmb; const float* __restrict__ psb;
    const float* __restrict__ dmb; const float* __restrict__ dsb;
    const float* __restrict__ bih; const float* __restrict__ bhh;
    const uint2* __restrict__ wq;
    float* __restrict__ partials;
};

// launch_bounds 2nd arg behaves as min BLOCKS/CU here (R5 evidence: (1024,4)->VGPR 64,
// (512,2)->VGPR 128). Grid is 160 blocks on 256 CUs -> 1 block/CU is all we ever get,
// so declare 1 and unlock the 256-VGPR budget the weight-resident design needs.
__global__ void __launch_bounds__(NTH, 1) vrnn6(P3s p) {
    const int tid = threadIdx.x;
    const int a = blockIdx.x >> 5;
    const int b0 = (blockIdx.x & 31) * 4;
    const int wave = tid >> 6;
    const int lane = tid & 63;
    const int o = wave * 16 + (lane & 15);   // output column 0..127
    const int k4 = lane >> 4;                // K-quarter / row id 0..3
    const bool k0 = (k4 == 0);

    __shared__ __align__(16) u16 U[4][160];          // [x2 y10 z16 pad4 h128]
    __shared__ __align__(16) u16 aA[4][128], aB[4][128], aC[4][128], aD[4][128];
    __shared__ float mue[4][16], sde[4][16], mup[4][16], sdp[4][16];
    __shared__ float xf[4][2], dmu[4][2], dsd[4][2];
    __shared__ uint2 whLDS[2048];   // 4 heads x 32q x 16
    __shared__ uint2 wdhLDS[128];   // 2 heads x 32q x 2
    __shared__ float red[NTH];

    const uint2* WA = p.wq + (size_t)a * AGU2;

    // ---- init LDS: zero U (pad + h), copy head weights ----
    for (int i = tid; i < 4 * 160; i += NTH) (&U[0][0])[i] = 0;
    for (int i = tid; i < 2048; i += NTH) whLDS[i] = WA[OF_H + i];
    if (tid < 128) wdhLDS[tid] = WA[OF_DH + tid];

    // ---- register-resident weights (loop-invariant, PINNED) ----
    uint2 wE1[10], wP1[10], wD1[10], wG0[10], wG1[10], wG2[10];
    uint2 wE2[8], wP2[8], wD2[8];
#pragma unroll
    for (int j = 0; j < 10; ++j) {
        int q = k4 * 10 + j;
        wE1[j] = WA[OF_E1 + q * 128 + o];
        wP1[j] = WA[OF_P1 + q * 128 + o];
        wD1[j] = WA[OF_D1 + q * 128 + o];
        wG0[j] = WA[OF_G + q * 384 + o];
        wG1[j] = WA[OF_G + q * 384 + 128 + o];
        wG2[j] = WA[OF_G + q * 384 + 256 + o];
    }
#pragma unroll
    for (int j = 0; j < 8; ++j) {
        int q = k4 * 8 + j;
        wE2[j] = WA[OF_E2 + q * 128 + o];
        wP2[j] = WA[OF_P2 + q * 128 + o];
        wD2[j] = WA[OF_D2 + q * 128 + o];
    }
#pragma unroll
    for (int j = 0; j < 10; ++j) {
        PINU2(wE1[j]); PINU2(wP1[j]); PINU2(wD1[j]);
        PINU2(wG0[j]); PINU2(wG1[j]); PINU2(wG2[j]);
    }
#pragma unroll
    for (int j = 0; j < 8; ++j) { PINU2(wE2[j]); PINU2(wP2[j]); PINU2(wD2[j]); }

    // ---- register-resident biases (pinned) ----
    float rbE1 = p.eb1[a * 128 + o], rbE2 = p.eb2[a * 128 + o];
    float rbP1 = p.pb1[a * 128 + o], rbP2 = p.pb2[a * 128 + o];
    float rbD1 = p.db1[a * 128 + o], rbD2 = p.db2[a * 128 + o];
    float rbI0 = p.bih[a * 384 + o], rbI1 = p.bih[a * 384 + 128 + o], rbI2 = p.bih[a * 384 + 256 + o];
    float rbH0 = p.bhh[a * 384 + o], rbH1 = p.bhh[a * 384 + 128 + o], rbH2 = p.bhh[a * 384 + 256 + o];
    const int headH = wave & 3, zdH = lane & 15, rH = (wave >> 2) * 2;
    float rbH = ((headH == 0) ? p.emb : (headH == 1) ? p.esb
               : (headH == 2) ? p.pmb : p.psb)[a * 16 + zdH];
    const int outD = tid >> 5, partD = tid & 31;
    const int headD = outD >> 3, subD = outD & 7, rD = subD >> 1, xdD = subD & 1;
    float rbDH = (headD ? p.dsb : p.dmb)[a * 2 + xdD];
    PINF(rbE1); PINF(rbE2); PINF(rbP1); PINF(rbP2); PINF(rbD1); PINF(rbD2);
    PINF(rbI0); PINF(rbI1); PINF(rbI2); PINF(rbH0); PINF(rbH1); PINF(rbH2);
    PINF(rbH); PINF(rbDH);

    // ---- per-row LDS base pointers (k4-offset folded in) ----
    const u16* Ub[4];  const u16* aAb[4]; const u16* aBb[4]; const u16* aCb[4]; const u16* aDb[4];
#pragma unroll
    for (int r = 0; r < 4; ++r) {
        Ub[r]  = &U[r][0]  + k4 * 40;   // 10 quads * 4 u16
        aAb[r] = &aA[r][0] + k4 * 32;   // 8 quads * 4 u16
        aBb[r] = &aB[r][0] + k4 * 32;
        aCb[r] = &aC[r][0] + k4 * 32;
        aDb[r] = &aD[r][0] + k4 * 32;
    }

    // ---- prefetch t=0 inputs into registers ----
    const int ry = tid / 10, jy = tid - ry * 10;            // tid<40
    const int rx = (tid - 40) >> 1, xdx = (tid - 40) & 1;   // 40<=tid<48
    const int re = tid >> 4, ze = tid & 15;                 // tid<64
    float ypre = 0.f, xpre = 0.f, epre = 0.f;
    if (tid < 40) ypre = p.y[0 * (B_ * 10) + (b0 + ry) * 10 + jy];
    else if (tid < 48) xpre = p.y[1 * (B_ * 10) + (b0 + rx) * 10 + a * 2 + xdx];
    if (tid < 64) epre = p.eps[(((size_t)0 * A_ + a) * B_ + (b0 + re)) * 16 + ze];

    float kl_acc = 0.f, nll_acc = 0.f, hnew = 0.f;

#pragma unroll 1
    for (int t = 0; t < NS; ++t) {
        const int tn = (t + 1 < NS) ? t + 1 : t;
        __syncthreads();
        // ---- P1: commit prefetched inputs, issue next prefetch ----
        if (tid < 40) {
            U[ry][2 + jy] = f2h(ypre);
            ypre = p.y[tn * (B_ * 10) + (b0 + ry) * 10 + jy];
        } else if (tid < 48) {
            U[rx][xdx] = f2h(xpre); xf[rx][xdx] = xpre;
            xpre = p.y[(tn + 1) * (B_ * 10) + (b0 + rx) * 10 + a * 2 + xdx];
        }
        __syncthreads();

        // ---- P2: enc1 + pri1 (shared U reads) ----
        {
            float aE[4], aP[4];
#pragma unroll
            for (int r = 0; r < 4; ++r) { aE[r] = k0 ? rbE1 : 0.f; aP[r] = k0 ? rbP1 : 0.f; }
#pragma unroll
            for (int pp = 0; pp < 5; ++pp) {
#pragma unroll
                for (int r = 0; r < 4; ++r) {
                    uint4 xv = *(const uint4*)(Ub[r] + pp * 8);
                    aE[r] = fdot2(wE1[2*pp].x,   xv.x, aE[r]);
                    aE[r] = fdot2(wE1[2*pp].y,   xv.y, aE[r]);
                    aE[r] = fdot2(wE1[2*pp+1].x, xv.z, aE[r]);
                    aE[r] = fdot2(wE1[2*pp+1].y, xv.w, aE[r]);
                    aP[r] = fdot2(wP1[2*pp].x,   xv.x, aP[r]);
                    aP[r] = fdot2(wP1[2*pp].y,   xv.y, aP[r]);
                    aP[r] = fdot2(wP1[2*pp+1].x, xv.z, aP[r]);
                    aP[r] = fdot2(wP1[2*pp+1].y, xv.w, aP[r]);
                }
            }
#pragma unroll
            for (int r = 0; r < 4; ++r) { RED16_32(aE[r]); RED16_32(aP[r]); }
            float vE = SEL4(k4, aE[0], aE[1], aE[2], aE[3]);
            float vP = SEL4(k4, aP[0], aP[1], aP[2], aP[3]);
            aA[k4][o] = f2h(fmaxf(vE, 0.f));
            aC[k4][o] = f2h(fmaxf(vP, 0.f));
        }
        __syncthreads();

        // ---- P3: enc2 (aA->aB), pri2 (aC->aD) ----
        {
            float aE[4], aP[4];
#pragma unroll
            for (int r = 0; r < 4; ++r) { aE[r] = k0 ? rbE2 : 0.f; aP[r] = k0 ? rbP2 : 0.f; }
#pragma unroll
            for (int pp = 0; pp < 4; ++pp) {
#pragma unroll
                for (int r = 0; r < 4; ++r) {
                    uint4 xa = *(const uint4*)(aAb[r] + pp * 8);
                    uint4 xc = *(const uint4*)(aCb[r] + pp * 8);
                    aE[r] = fdot2(wE2[2*pp].x,   xa.x, aE[r]);
                    aE[r] = fdot2(wE2[2*pp].y,   xa.y, aE[r]);
                    aE[r] = fdot2(wE2[2*pp+1].x, xa.z, aE[r]);
                    aE[r] = fdot2(wE2[2*pp+1].y, xa.w, aE[r]);
                    aP[r] = fdot2(wP2[2*pp].x,   xc.x, aP[r]);
                    aP[r] = fdot2(wP2[2*pp].y,   xc.y, aP[r]);
                    aP[r] = fdot2(wP2[2*pp+1].x, xc.z, aP[r]);
                    aP[r] = fdot2(wP2[2*pp+1].y, xc.w, aP[r]);
                }
            }
#pragma unroll
            for (int r = 0; r < 4; ++r) { RED16_32(aE[r]); RED16_32(aP[r]); }
            float vE = SEL4(k4, aE[0], aE[1], aE[2], aE[3]);
            float vP = SEL4(k4, aP[0], aP[1], aP[2], aP[3]);
            aB[k4][o] = f2h(fmaxf(vE, 0.f));
            aD[k4][o] = f2h(fmaxf(vP, 0.f));
        }
        __syncthreads();

        // ---- P4: 4 gaussian heads (128->16), weights from LDS ----
        {
            const u16* s0p = (headH < 2) ? &aB[rH][0]     : &aD[rH][0];
            const u16* s1p = (headH < 2) ? &aB[rH + 1][0] : &aD[rH + 1][0];
            float e0 = k0 ? rbH : 0.f, e1 = k0 ? rbH : 0.f;
#pragma unroll
            for (int pp = 0; pp < 4; ++pp) {
                int q = k4 * 8 + 2 * pp;
                uint2 w0 = whLDS[headH * 512 + q * 16 + zdH];
                uint2 w1 = whLDS[headH * 512 + (q + 1) * 16 + zdH];
                uint4 x0 = *(const uint4*)(s0p + k4 * 32 + pp * 8);
                uint4 x1 = *(const uint4*)(s1p + k4 * 32 + pp * 8);
                e0 = fdot2(w0.x, x0.x, e0); e0 = fdot2(w0.y, x0.y, e0);
                e0 = fdot2(w1.x, x0.z, e0); e0 = fdot2(w1.y, x0.w, e0);
                e1 = fdot2(w0.x, x1.x, e1); e1 = fdot2(w0.y, x1.y, e1);
                e1 = fdot2(w1.x, x1.z, e1); e1 = fdot2(w1.y, x1.w, e1);
            }
            RED16_32(e0); RED16_32(e1);
            if (k4 < 2) {
                float v = (k4 == 0) ? e0 : e1;
                int r = rH + k4;
                if (headH == 0)      mue[r][zdH] = v;
                else if (headH == 1) sde[r][zdH] = softplusf_(v);
                else if (headH == 2) mup[r][zdH] = v;
                else                 sdp[r][zdH] = softplusf_(v);
            }
        }
        __syncthreads();

        // ---- P5: z sample + KL (eps was prefetched) ----
        if (tid < 64) {
            float em = mue[re][ze], es = sde[re][ze], pm = mup[re][ze], ps = sdp[re][ze];
            float zv = fmaf(epre, es, em);
            U[re][12 + ze] = f2h(zv);
            float dm = em - pm;
            kl_acc += 0.5f * (2.f * (logf(ps) - logf(es)) + (es * es + dm * dm) / (ps * ps) - 1.f);
            epre = p.eps[(((size_t)tn * A_ + a) * B_ + (b0 + re)) * 16 + ze];
        }
        __syncthreads();

        // ---- P6: dec1 + GRU (shared U reads) ----
        {
            float aO[4], s0[4], s1[4], g2a[4], g2b[4];
#pragma unroll
            for (int r = 0; r < 4; ++r) {
                aO[r]  = k0 ? rbD1 : 0.f;
                s0[r]  = k0 ? (rbI0 + rbH0) : 0.f;
                s1[r]  = k0 ? (rbI1 + rbH1) : 0.f;
                g2a[r] = k0 ? rbI2 : 0.f;
                g2b[r] = k0 ? rbH2 : 0.f;
            }
#pragma unroll
            for (int pp = 0; pp < 5; ++pp) {
#pragma unroll
                for (int r = 0; r < 4; ++r) {
                    uint4 xv = *(const uint4*)(Ub[r] + pp * 8);
                    aO[r] = fdot2(wD1[2*pp].x,   xv.x, aO[r]);
                    aO[r] = fdot2(wD1[2*pp].y,   xv.y, aO[r]);
                    aO[r] = fdot2(wD1[2*pp+1].x, xv.z, aO[r]);
                    aO[r] = fdot2(wD1[2*pp+1].y, xv.w, aO[r]);
                    s0[r] = fdot2(wG0[2*pp].x,   xv.x, s0[r]);
                    s0[r] = fdot2(wG0[2*pp].y,   xv.y, s0[r]);
                    s0[r] = fdot2(wG0[2*pp+1].x, xv.z, s0[r]);
                    s0[r] = fdot2(wG0[2*pp+1].y, xv.w, s0[r]);
                    s1[r] = fdot2(wG1[2*pp].x,   xv.x, s1[r]);
                    s1[r] = fdot2(wG1[2*pp].y,   xv.y, s1[r]);
                    s1[r] = fdot2(wG1[2*pp+1].x, xv.z, s1[r]);
                    s1[r] = fdot2(wG1[2*pp+1].y, xv.w, s1[r]);
                    // gate-2: pairs 0-3 cover u<32 (ih region for k4==0), pair 4 covers h
                    float& g2 = (pp < 4) ? g2a[r] : g2b[r];
                    g2 = fdot2(wG2[2*pp].x,   xv.x, g2);
                    g2 = fdot2(wG2[2*pp].y,   xv.y, g2);
                    g2 = fdot2(wG2[2*pp+1].x, xv.z, g2);
                    g2 = fdot2(wG2[2*pp+1].y, xv.w, g2);
                }
            }
            float gi2[4], gh2[4];
#pragma unroll
            for (int r = 0; r < 4; ++r) {
                gi2[r] = k0 ? g2a[r] : 0.f;
                gh2[r] = k0 ? g2b[r] : (g2a[r] + g2b[r]);
            }
#pragma unroll
            for (int r = 0; r < 4; ++r) {
                RED16_32(aO[r]); RED16_32(s0[r]); RED16_32(s1[r]);
                RED16_32(gi2[r]); RED16_32(gh2[r]);
            }
            float vD = SEL4(k4, aO[0], aO[1], aO[2], aO[3]);
            float rs = SEL4(k4, s0[0], s0[1], s0[2], s0[3]);
            float zs = SEL4(k4, s1[0], s1[1], s1[2], s1[3]);
            float i2 = SEL4(k4, gi2[0], gi2[1], gi2[2], gi2[3]);
            float hh2 = SEL4(k4, gh2[0], gh2[1], gh2[2], gh2[3]);
            float rr = sigmoidf_(rs);
            float zz = sigmoidf_(zs);
            float nn = tanhf(fmaf(rr, hh2, i2));
            float hold = h2f(U[k4][32 + o]);
            hnew = fmaf(zz, hold - nn, nn);
            aA[k4][o] = f2h(fmaxf(vD, 0.f));
        }
        __syncthreads();

        // ---- P7: dec2 (aA -> aB) ----
        {
            float aE[4];
#pragma unroll
            for (int r = 0; r < 4; ++r) aE[r] = k0 ? rbD2 : 0.f;
#pragma unroll
            for (int pp = 0; pp < 4; ++pp) {
#pragma unroll
                for (int r = 0; r < 4; ++r) {
                    uint4 xa = *(const uint4*)(aAb[r] + pp * 8);
                    aE[r] = fdot2(wD2[2*pp].x,   xa.x, aE[r]);
                    aE[r] = fdot2(wD2[2*pp].y,   xa.y, aE[r]);
                    aE[r] = fdot2(wD2[2*pp+1].x, xa.z, aE[r]);
                    aE[r] = fdot2(wD2[2*pp+1].y, xa.w, aE[r]);
                }
            }
#pragma unroll
            for (int r = 0; r < 4; ++r) RED16_32(aE[r]);
            float vE = SEL4(k4, aE[0], aE[1], aE[2], aE[3]);
            aB[k4][o] = f2h(fmaxf(vE, 0.f));
        }
        __syncthreads();

        // ---- P8: h write + dec heads (128->2) ----
        U[k4][32 + o] = f2h(hnew);
        {
            uint2 w = wdhLDS[headD * 64 + partD * 2 + xdD];
            uint2 xa = *(const uint2*)(&aB[rD][0] + partD * 4);
            float s = fdot2(w.x, xa.x, 0.f);
            s = fdot2(w.y, xa.y, s);
            s += __shfl_xor(s, 1); s += __shfl_xor(s, 2); s += __shfl_xor(s, 4);
            s += __shfl_xor(s, 8); s += __shfl_xor(s, 16);
            if (partD == 0) {
                float v = rbDH + s;
                if (headD) dsd[rD][xdD] = softplusf_(v);
                else       dmu[rD][xdD] = v;
            }
        }
        __syncthreads();

        // ---- P9: NLL ----
        if (tid < 8) {
            int r = tid >> 1, xd = tid & 1;
            float d = xf[r][xd] - dmu[r][xd];
            float sd = dsd[r][xd];
            nll_acc += 0.5f * (d * d / (sd * sd) + 2.f * logf(sd) + LOG2PI_F);
        }
    }

    // ---- block reductions ----
    __syncthreads();
    red[tid] = kl_acc; __syncthreads();
    for (int s2 = NTH / 2; s2 > 0; s2 >>= 1) {
        if (tid < s2) red[tid] += red[tid + s2];
        __syncthreads();
    }
    if (tid == 0) p.partials[blockIdx.x] = red[0];
    __syncthreads();
    red[tid] = nll_acc; __syncthreads();
    for (int s2 = NTH / 2; s2 > 0; s2 >>= 1) {
        if (tid < s2) red[tid] += red[tid + s2];
        __syncthreads();
    }
    if (tid == 0) p.partials[NWG + blockIdx.x] = red[0];
}

// ---------------- prep: pack weights into unified zero-padded f16 quads ----------------
struct PrepP {
    const float* eW1; const float* pW1; const float* dW1;
    const float* wih; const float* whh;
    const float* eW2; const float* pW2; const float* dW2;
    const float* hW[4];   // em es pm ps
    const float* dHW[2];  // dm ds
    uint2* dst;
};

__global__ void prep3(PrepP pp) {
    const int jod[13]  = {128,128,128,384, 128,128,128, 16,16,16,16, 2,2};
    const int jnq[13]  = {40,40,40,40, 32,32,32, 32,32,32,32, 32,32};
    const int jdst[13] = {OF_E1,OF_P1,OF_D1,OF_G, OF_E2,OF_P2,OF_D2,
                          OF_H,OF_H+512,OF_H+1024,OF_H+1536, OF_DH,OF_DH+64};
    const int jkt[3]   = {140,138,154};

    int job = blockIdx.y;
    int od = jod[job], nq = jnq[job];
    int total = A_ * nq * od;
    int idx = blockIdx.x * 256 + threadIdx.x;
    if (idx >= total) return;
    int a = idx / (nq * od);
    int rem = idx - a * (nq * od);
    int q = rem / od;
    int c = rem - q * od;

    float v[4];
#pragma unroll
    for (int i = 0; i < 4; ++i) {
        int k = 4 * q + i;
        float val = 0.f;
        if (job < 3) {
            // unified u index -> source row
            int sk = -1;
            if (job == 0)      sk = (k < 12) ? k : (k >= 32 ? k - 20 : -1);
            else if (job == 1) sk = (k >= 2 && k < 12) ? k - 2 : (k >= 32 ? k - 22 : -1);
            else               sk = (k >= 2 && k < 28) ? k - 2 : (k >= 32 ? k - 6 : -1);
            const float* s = (job == 0) ? pp.eW1 : (job == 1) ? pp.pW1 : pp.dW1;
            if (sk >= 0) val = s[((size_t)a * jkt[job] + sk) * 128 + c];
        } else if (job == 3) {
            // GRU unified: c = gate index 0..383
            if (k < 2)                  val = pp.wih[((size_t)a * 384 + c) * 18 + k];
            else if (k >= 12 && k < 28) val = pp.wih[((size_t)a * 384 + c) * 18 + (k - 10)];
            else if (k >= 32)           val = pp.whh[((size_t)a * 384 + c) * 128 + (k - 32)];
        } else {
            const float* s = (job == 4) ? pp.eW2 : (job == 5) ? pp.pW2 : (job == 6) ? pp.dW2
                           : (job <= 10) ? pp.hW[job - 7] : pp.dHW[job - 11];
            val = s[((size_t)a * 128 + k) * od + c];
        }
        v[i] = val;
    }
    u32 lo = (u32)f2h(v[0]) | ((u32)f2h(v[1]) << 16);
    u32 hi = (u32)f2h(v[2]) | ((u32)f2h(v[3]) << 16);
    pp.dst[(size_t)a * AGU2 + jdst[job] + q * od + c] = make_uint2(lo, hi);
}

__global__ void finish_kernel(const float* __restrict__ partials, float* __restrict__ out) {
    __shared__ float red[256];
    int tid = threadIdx.x;
    red[tid] = (tid < NWG) ? partials[tid] : 0.f;
    __syncthreads();
    for (int s2 = 128; s2 > 0; s2 >>= 1) {
        if (tid < s2) red[tid] += red[tid + s2];
        __syncthreads();
    }
    if (tid == 0) out[0] = red[0];
    __syncthreads();
    red[tid] = (tid < NWG) ? partials[NWG + tid] : 0.f;
    __syncthreads();
    for (int s2 = 128; s2 > 0; s2 >>= 1) {
        if (tid < s2) red[tid] += red[tid + s2];
        __syncthreads();
    }
    if (tid == 0) out[1] = red[0];
}

extern "C" void kernel_launch(void* const* d_in, const int* in_sizes, int n_in,
                              void* d_out, int out_size, void* d_ws, size_t ws_size,
                              hipStream_t stream) {
    float* partials = (float*)d_ws;                 // 320 floats
    uint2* wq = (uint2*)((char*)d_ws + 4096);       // packed weights, ~1.81 MB

    PrepP pp;
    pp.eW1 = (const float*)d_in[2];
    pp.pW1 = (const float*)d_in[10];
    pp.dW1 = (const float*)d_in[18];
    pp.wih = (const float*)d_in[26];
    pp.whh = (const float*)d_in[27];
    pp.eW2 = (const float*)d_in[4];
    pp.pW2 = (const float*)d_in[12];
    pp.dW2 = (const float*)d_in[20];
    pp.hW[0] = (const float*)d_in[6];   // emW
    pp.hW[1] = (const float*)d_in[8];   // esW
    pp.hW[2] = (const float*)d_in[14];  // pmW
    pp.hW[3] = (const float*)d_in[16];  // psW
    pp.dHW[0] = (const float*)d_in[22]; // dmW
    pp.dHW[1] = (const float*)d_in[24]; // dsW
    pp.dst = wq;
    // max job total = 5*40*384 = 76800 -> 300 blocks x 256, y = 13 jobs
    prep3<<<dim3(300, 13), 256, 0, stream>>>(pp);

    P3s p;
    p.y   = (const float*)d_in[0];
    p.eps = (const float*)d_in[1];
    p.eb1 = (const float*)d_in[3];  p.eb2 = (const float*)d_in[5];
    p.emb = (const float*)d_in[7];  p.esb = (const float*)d_in[9];
    p.pb1 = (const float*)d_in[11]; p.pb2 = (const float*)d_in[13];
    p.pmb = (const float*)d_in[15]; p.psb = (const float*)d_in[17];
    p.db1 = (const float*)d_in[19]; p.db2 = (const float*)d_in[21];
    p.dmb = (const float*)d_in[23]; p.dsb = (const float*)d_in[25];
    p.bih = (const float*)d_in[28]; p.bhh = (const float*)d_in[29];
    p.wq = wq;
    p.partials = partials;

    vrnn6<<<NWG, NTH, 0, stream>>>(p);
    finish_kernel<<<1, 256, 0, stream>>>(partials, (float*)d_out);
}